// Round 10
// baseline (280.986 us; speedup 1.0000x reference)
//
#include <hip/hip_runtime.h>
#include <hip/hip_cooperative_groups.h>

typedef unsigned short u16;
typedef unsigned int   u32;

#define BB 4
#define CC 256
#define CI 128
#define NN 8192
#define N2 2048

// ws layout (bytes).
#define PHI_OFF   0u           // phi pooled fp16 [b][m][ci]: 2,097,152
#define CAN0_OFF  2097152u
#define GP_OFF    2097168u     // g pooled fp16 [b][ci][m]: 2,097,152
#define CAN1_OFF  4194320u
#define THB_OFF   4194336u     // theta fp16 b=2,3: 4,194,304
#define CAN2_OFF  8388640u
#define FLAG_OFF  8388644u     // (dead cell, kept for layout stability)
#define WFH_OFF   8388672u     // wf fp16 [256][128]: 65,536
#define PART_OFF  8454208u     // probe per-block partials: 512*4 = 2,048
#define WS_NEED   8456256u     // < 10,485,808 proven available

#define CAN0V 0xC0FFEE01u
#define CAN1V 0xC0FFEE02u
#define CAN2V 0xC0FFEE03u

#define LOG2E 1.4426950408889634f

typedef _Float16 f16;
typedef f16 f16x8 __attribute__((ext_vector_type(8)));
typedef float f32x4 __attribute__((ext_vector_type(4)));

namespace cg = cooperative_groups;

__device__ __forceinline__ u16 f2h(float f) {
    _Float16 h = (_Float16)f;
    return __builtin_bit_cast(u16, h);
}
__device__ __forceinline__ float h2f(u16 u) {
    return (float)__builtin_bit_cast(_Float16, u);
}
__device__ __forceinline__ u32 pk2h(float a, float b) {
    return (u32)f2h(a) | ((u32)f2h(b) << 16);
}

// ---------------------------------------------------------------------------
__global__ __launch_bounds__(256) void fill_constf(float* out, float v, int n)
{
    int i = blockIdx.x * 256 + threadIdx.x;
    if (i < n) out[i] = v;
}

// ---------------------------------------------------------------------------
// K1: projections via compensated fp16 MFMA. R10: probe (x dtype check) and
// prep (W hi/lo split, wf->fp16) folded in — W split happens during staging,
// mb==0 blocks probe their x words (full coverage) into part[], mb==1/b==0
// blocks convert wf. Removes 2 kernels + whi/wlo buffers.
// ---------------------------------------------------------------------------
__global__ __launch_bounds__(256) void proj_mfma(
    const float* __restrict__ x,
    const float* __restrict__ b0v, const float* __restrict__ b1v,
    const float* __restrict__ b2v,
    const float* __restrict__ w0, const float* __restrict__ w1,
    const float* __restrict__ w2, const float* __restrict__ wf,
    u16* __restrict__ thA, u16* __restrict__ thB,
    u16* __restrict__ phH, u16* __restrict__ gH,
    u16* __restrict__ wfh, u32* __restrict__ part,
    u32* __restrict__ ws32)
{
    __shared__ __align__(16) u16 smem[24576];   // 48 KB
    int nb2 = blockIdx.x, mb = blockIdx.y, b = blockIdx.z;
    int tid = threadIdx.x;
    int lane = tid & 63, wid = tid >> 6, l15 = lane & 15, lg = lane >> 4;
    int n0 = nb2 * 64;

    const float* Bv = mb == 0 ? b0v : (mb == 1 ? b1v : b2v);
    const float* W  = mb == 0 ? w0 : (mb == 1 ? w1 : w2);

    int n_l = tid & 63, cg_ = tid >> 6;
    const float* xp = x + ((size_t)(b * CC + cg_ * 8)) * NN + n0 + n_l;
    int wci = tid >> 2, wkc = tid & 3;
    const float* wp = W + wci * 256 + wkc * 8;   // fp32 weights

    float xr[8];
    float4 wa0, wa1, wb0, wb1;
    bool ffacc = false, nzacc = false;

#define PLOAD(s) do {                                                          \
    _Pragma("unroll") for (int j = 0; j < 8; j++)                              \
        xr[j] = xp[(size_t)((s) * 32 + j) * NN];                               \
    wa0 = ((const float4*)(wp + (s) * 32))[0];                                 \
    wa1 = ((const float4*)(wp + (s) * 32))[1];                                 \
    wb0 = ((const float4*)(wp + 16384 + (s) * 32))[0];                         \
    wb1 = ((const float4*)(wp + 16384 + (s) * 32))[1];                         \
} while (0)

#define PWRITE(bf) do {                                                        \
    u16* bp = smem + (bf) * 12288;                                             \
    u32 hw[4], lw[4];                                                          \
    _Pragma("unroll") for (int j = 0; j < 4; j++) {                            \
        u16 h0 = f2h(xr[2 * j]), h1 = f2h(xr[2 * j + 1]);                      \
        u16 q0 = f2h(xr[2 * j] - h2f(h0)), q1 = f2h(xr[2 * j + 1] - h2f(h1));  \
        hw[j] = (u32)h0 | ((u32)h1 << 16);                                     \
        lw[j] = (u32)q0 | ((u32)q1 << 16);                                     \
    }                                                                          \
    if (mb == 0) {                                                             \
        _Pragma("unroll") for (int j = 0; j < 8; j++) {                        \
            u32 wb_ = __float_as_uint(xr[j]);                                  \
            u32 lo = wb_ & 0xffffu, hi = wb_ >> 16;                            \
            ffacc |= ((lo & 0x7f80u) == 0x7f80u) || ((hi & 0x7f80u) == 0x7f80u); \
            nzacc |= (lo != 0u);                                               \
        }                                                                      \
    }                                                                          \
    int xi = (n_l * 32 + cg_ * 8) ^ (((n_l >> 1) & 3) << 3);                   \
    *(uint4*)&bp[xi]        = make_uint4(hw[0], hw[1], hw[2], hw[3]);          \
    *(uint4*)&bp[2048 + xi] = make_uint4(lw[0], lw[1], lw[2], lw[3]);          \
    float wva[8] = {wa0.x, wa0.y, wa0.z, wa0.w, wa1.x, wa1.y, wa1.z, wa1.w};   \
    float wvb[8] = {wb0.x, wb0.y, wb0.z, wb0.w, wb1.x, wb1.y, wb1.z, wb1.w};   \
    u32 ha[4], la[4], hb[4], lb[4];                                            \
    _Pragma("unroll") for (int j = 0; j < 4; j++) {                            \
        u16 h0 = f2h(wva[2 * j]), h1 = f2h(wva[2 * j + 1]);                    \
        ha[j] = (u32)h0 | ((u32)h1 << 16);                                     \
        la[j] = pk2h(wva[2 * j] - h2f(h0), wva[2 * j + 1] - h2f(h1));          \
        u16 g0 = f2h(wvb[2 * j]), g1 = f2h(wvb[2 * j + 1]);                    \
        hb[j] = (u32)g0 | ((u32)g1 << 16);                                     \
        lb[j] = pk2h(wvb[2 * j] - h2f(g0), wvb[2 * j + 1] - h2f(g1));          \
    }                                                                          \
    int wi = (wci * 32 + wkc * 8) ^ (((wci >> 1) & 3) << 3);                   \
    *(uint4*)&bp[4096 + wi]        = make_uint4(ha[0], ha[1], ha[2], ha[3]);   \
    *(uint4*)&bp[4096 + wi + 2048] = make_uint4(hb[0], hb[1], hb[2], hb[3]);   \
    *(uint4*)&bp[8192 + wi]        = make_uint4(la[0], la[1], la[2], la[3]);   \
    *(uint4*)&bp[8192 + wi + 2048] = make_uint4(lb[0], lb[1], lb[2], lb[3]);   \
} while (0)

    f32x4 acc[2][4];
#pragma unroll
    for (int i = 0; i < 2; i++)
#pragma unroll
        for (int j = 0; j < 4; j++) acc[i][j] = (f32x4){0.f, 0.f, 0.f, 0.f};

    PLOAD(0);
    PWRITE(0);
    PLOAD(1);
    __syncthreads();

    for (int t = 0; t < 8; t++) {
        int cur = t & 1;
        if (t + 1 < 8) PWRITE(cur ^ 1);
        if (t + 2 < 8) PLOAD(t + 2);
        const u16* bp = smem + cur * 12288;
        f16x8 ah[2], al[2], bh[4], bl[4];
#pragma unroll
        for (int rt = 0; rt < 2; rt++) {
            int r = wid * 32 + rt * 16 + l15;
            int idx = (r * 32 + lg * 8) ^ (((r >> 1) & 3) << 3);
            ah[rt] = *(const f16x8*)&bp[4096 + idx];
            al[rt] = *(const f16x8*)&bp[8192 + idx];
        }
#pragma unroll
        for (int ct = 0; ct < 4; ct++) {
            int n = ct * 16 + l15;
            int idx = (n * 32 + lg * 8) ^ (((n >> 1) & 3) << 3);
            bh[ct] = *(const f16x8*)&bp[idx];
            bl[ct] = *(const f16x8*)&bp[2048 + idx];
        }
#pragma unroll
        for (int rt = 0; rt < 2; rt++)
#pragma unroll
            for (int ct = 0; ct < 4; ct++) {
                acc[rt][ct] = __builtin_amdgcn_mfma_f32_16x16x32_f16(ah[rt], bh[ct], acc[rt][ct], 0, 0, 0);
                acc[rt][ct] = __builtin_amdgcn_mfma_f32_16x16x32_f16(ah[rt], bl[ct], acc[rt][ct], 0, 0, 0);
                acc[rt][ct] = __builtin_amdgcn_mfma_f32_16x16x32_f16(al[rt], bh[ct], acc[rt][ct], 0, 0, 0);
            }
        __syncthreads();
    }
#undef PLOAD
#undef PWRITE

    // probe partial per wave -> LDS tail (beyond ot's 33,792 B)
    u32* redp = (u32*)((char*)smem + 34816);
    {
        u32 wm = (__any(ffacc) ? 1u : 0u) | (__any(nzacc) ? 2u : 0u);
        if (mb == 0 && lane == 0) redp[wid] = wm;
    }

    float* ot = (float*)smem;   // [64][132]
#pragma unroll
    for (int rt = 0; rt < 2; rt++) {
        int cb = wid * 32 + rt * 16 + lg * 4;
        float4 b4 = *(const float4*)&Bv[cb];
#pragma unroll
        for (int ct = 0; ct < 4; ct++) {
            int n = ct * 16 + l15;
            float4 v = make_float4(acc[rt][ct][0] + b4.x, acc[rt][ct][1] + b4.y,
                                   acc[rt][ct][2] + b4.z, acc[rt][ct][3] + b4.w);
            *(float4*)&ot[n * 132 + cb] = v;
        }
    }
    __syncthreads();

    int mb0 = (nb2 >> 4) * 256 + (nb2 & 15) * 16;

    if (mb == 0) {
        int nl = tid >> 2, sg = (tid & 3) * 32;
        u16* base = (b < 2) ? thA : thB;
        u16* dst = base + ((size_t)((b & 1) * NN + n0 + nl)) * CI + sg;
        const float* src = &ot[nl * 132 + sg];
#pragma unroll
        for (int i = 0; i < 4; i++) {
            u32 w[4];
#pragma unroll
            for (int j = 0; j < 4; j++)
                w[j] = (u32)f2h(src[i * 8 + 2 * j] * LOG2E) |
                       ((u32)f2h(src[i * 8 + 2 * j + 1] * LOG2E) << 16);
            ((uint4*)dst)[i] = make_uint4(w[0], w[1], w[2], w[3]);
        }
        if (tid == 0)
            part[b * 128 + nb2] = redp[0] | redp[1] | redp[2] | redp[3];
    } else if (mb == 1) {
        int ml = tid >> 4, cs = (tid & 15) * 8;
        int r0 = 2 * ml, r1 = r0 + 1, r2 = 32 + 2 * ml, r3 = r2 + 1;
        float pv[8];
#pragma unroll
        for (int j = 0; j < 8; j++)
            pv[j] = fmaxf(fmaxf(ot[r0 * 132 + cs + j], ot[r1 * 132 + cs + j]),
                          fmaxf(ot[r2 * 132 + cs + j], ot[r3 * 132 + cs + j]));
        u32 w[4];
#pragma unroll
        for (int j = 0; j < 4; j++)
            w[j] = (u32)f2h(pv[2 * j]) | ((u32)f2h(pv[2 * j + 1]) << 16);
        *(uint4*)(phH + ((size_t)(b * N2 + mb0 + ml)) * CI + cs) =
            make_uint4(w[0], w[1], w[2], w[3]);
        if (b == 0) wfh[nb2 * 256 + tid] = f2h(wf[nb2 * 256 + tid]);
    } else {
        int gci = tid >> 1, half = tid & 1;
        u32 res[4];
#pragma unroll
        for (int p = 0; p < 4; p++) {
            int m0 = half * 8 + 2 * p, m1 = m0 + 1;
            float v0 = fmaxf(fmaxf(ot[(2 * m0) * 132 + gci], ot[(2 * m0 + 1) * 132 + gci]),
                             fmaxf(ot[(32 + 2 * m0) * 132 + gci], ot[(33 + 2 * m0) * 132 + gci]));
            float v1 = fmaxf(fmaxf(ot[(2 * m1) * 132 + gci], ot[(2 * m1 + 1) * 132 + gci]),
                             fmaxf(ot[(32 + 2 * m1) * 132 + gci], ot[(33 + 2 * m1) * 132 + gci]));
            res[p] = (u32)f2h(v0) | ((u32)f2h(v1) << 16);
        }
        *(uint4*)(gH + ((size_t)(b * CI + gci)) * N2 + mb0 + half * 8) =
            make_uint4(res[0], res[1], res[2], res[3]);
    }
    if (nb2 == 0 && mb == 0 && b == 0 && tid == 0) {
        ws32[CAN0_OFF / 4] = CAN0V;
        ws32[CAN1_OFF / 4] = CAN1V;
        ws32[CAN2_OFF / 4] = CAN2V;
    }
}

// ---------------------------------------------------------------------------
// K2 (fused): flash attention + final conv, swapped-operand QK^T (validated
// R9). R10: SINGLE cooperative launch, grid (128,4) = 512 blocks = 2/CU.
// grid.sync() after theta loads (vmcnt-drained) closes the thA-in-d_out
// hazard: all theta reads complete before any out-write. coop=0 fallback
// keeps the proven 2-launch path. Flag computed from probe partials here.
// ---------------------------------------------------------------------------
__global__ __launch_bounds__(512, 4) void attn_fused(
    const u16* __restrict__ thA, const u16* __restrict__ thB,
    const u16* __restrict__ phH, const u16* __restrict__ gH,
    const u16* __restrict__ wfh,
    const float* __restrict__ bfi, const float* __restrict__ gam,
    const float* __restrict__ bet, const float* __restrict__ mea,
    const float* __restrict__ varr, const float* __restrict__ x,
    const u32* __restrict__ part, const u32* __restrict__ ws32,
    float* __restrict__ out, int b0, int coop)
{
    __shared__ __align__(16) u16 kv_s[4][8192];   // [grp*2+buf]: phi 8KB | V 8KB
    __shared__ __align__(16) u16 p_s[8][512];     // per wave: P^T [16 q][32 key]
    __shared__ float cmcl[128];                   // cm[64] | cl[64]; u32 scratch early
    __shared__ int flag;
    float* cm = cmcl;
    float* cl = cmcl + 64;

    int tid = threadIdx.x;
    int lane = tid & 63, wid = tid >> 6;
    int l15 = lane & 15, lg = lane >> 4;
    int grp = wid >> 2;          // KV half
    int wq  = wid & 3;           // q sub-tile (16 rows) within group
    int gtid = tid & 255;        // tid within group
    int qb = blockIdx.x, b = b0 + blockIdx.y;

    // ---- combine probe partials (512 u32, L2-hot) -> flag ----
    {
        u32* cmU = (u32*)cmcl;
        if (tid < 128) {
            uint4 q4 = ((const uint4*)part)[tid];
            cmU[tid] = q4.x | q4.y | q4.z | q4.w;
        }
        __syncthreads();
        if (tid < 16) {
            u32 m = 0;
#pragma unroll
            for (int i = 0; i < 8; i++) m |= cmU[tid * 8 + i];
            cmU[tid] = m;
        }
        __syncthreads();
        if (tid == 0) {
            u32 pf = 0;
#pragma unroll
            for (int i = 0; i < 16; i++) pf |= cmU[i];
            bool ws_ok = ws32[CAN0_OFF / 4] == CAN0V && ws32[CAN1_OFF / 4] == CAN1V &&
                         ws32[CAN2_OFF / 4] == CAN2V;
            bool is_bf16_input = ((pf & 1u) == 0u) && ((pf & 2u) != 0u);
            flag = is_bf16_input ? 2 : (ws_ok ? 0 : 1);
        }
    }

    const u16* phB = phH + (size_t)b * N2 * CI;
    const u16* gB  = gH + (size_t)b * CI * N2;

    uint4 rph0, rph1, rv0, rv1;

#define LOADKV(k0) do {                                                                  \
    rph0 = *(const uint4*)(phB + ((size_t)((k0) + (gtid >> 4))) * CI + (gtid & 15) * 8); \
    rph1 = *(const uint4*)(phB + ((size_t)((k0) + 16 + (gtid >> 4))) * CI + (gtid & 15) * 8); \
    rv0  = *(const uint4*)(gB + (size_t)(gtid >> 2) * N2 + (k0) + (gtid & 3) * 8);       \
    rv1  = *(const uint4*)(gB + (size_t)(64 + (gtid >> 2)) * N2 + (k0) + (gtid & 3) * 8); \
} while (0)

#define WRITEKV(buf) do {                                                                \
    u16* ph_d = kv_s[grp * 2 + (buf)]; u16* v_d = ph_d + 4096;                           \
    { int key = gtid >> 4;        int c8 = gtid & 15;                                    \
      *(uint4*)&ph_d[(key * 128 + c8 * 8) ^ ((key & 7) << 3)] = rph0; }                  \
    { int key = 16 + (gtid >> 4); int c8 = gtid & 15;                                    \
      *(uint4*)&ph_d[(key * 128 + c8 * 8) ^ ((key & 7) << 3)] = rph1; }                  \
    { int d = gtid >> 2;        int m8 = (gtid & 3) * 8;                                 \
      *(uint4*)&v_d[(d * 32 + m8) ^ (((d >> 1) & 3) << 3)] = rv0; }                      \
    { int d = 64 + (gtid >> 2); int m8 = (gtid & 3) * 8;                                 \
      *(uint4*)&v_d[(d * 32 + m8) ^ (((d >> 1) & 3) << 3)] = rv1; }                      \
} while (0)

    // theta fragments: direct global->reg (B operand of swapped QK^T)
    f16x8 ath[4];
    {
        const u16* thbase = (b < 2) ? thA : thB;
        const u16* tp = thbase + ((size_t)((b & 1) * NN + qb * 64 + wq * 16 + l15)) * CI;
#pragma unroll
        for (int ks = 0; ks < 4; ks++)
            ath[ks] = *(const f16x8*)(tp + ks * 32 + lg * 8);
    }
    int kbase = grp * 1024;
    LOADKV(kbase);
    WRITEKV(0);
    LOADKV(kbase + 32);

    if (coop) {
        // all theta reads (and prefetches) architecturally complete before any
        // block may proceed to out-writes that alias thA in d_out.
        asm volatile("s_waitcnt vmcnt(0)" ::: "memory");
        cg::this_grid().sync();
    }
    __syncthreads();

    if (flag) {   // sentinel path (dtype model wrong / ws corrupt)
        float sig = flag == 2 ? 40000.f : 30000.f;
        if (tid < 256) {
            size_t rowb = ((size_t)(b * CC + tid)) * NN + qb * 64;
            for (int n = 0; n < 64; n++) out[rowb + n] = sig;
        }
        return;
    }

    f16x8 ones;
#pragma unroll
    for (int i = 0; i < 8; i++) ones[i] = (f16)1.0f;

    // Y^T: lane owns q = wq*16 + l15; Y[dt][r] = y[q][d = dt*16 + lg*4 + r]
    f32x4 Y[8];
#pragma unroll
    for (int i = 0; i < 8; i++) Y[i] = (f32x4){0.f, 0.f, 0.f, 0.f};
    f32x4 Yl = {0.f, 0.f, 0.f, 0.f};   // all 4 regs = l[q]
    float m_run = -1e30f;              // per-lane scalar (one q-row)

    int psw = (l15 & 7) << 3;
    u16* pw = p_s[wid];

    for (int t = 0; t < 32; t++) {
        int cur = t & 1;
        if (t + 1 < 32) WRITEKV(cur ^ 1);
        if (t + 2 < 32) LOADKV(kbase + (t + 2) * 32);

        const u16* ph_c = kv_s[grp * 2 + cur];
        const u16* v_c  = ph_c + 4096;

        // ---- QK^T swapped: S^T[key][q], lane owns q=l15
        f32x4 S0 = {0.f, 0.f, 0.f, 0.f}, S1 = {0.f, 0.f, 0.f, 0.f};
#pragma unroll
        for (int ks = 0; ks < 4; ks++) {
            f16x8 bf0 = *(const f16x8*)&ph_c[(l15 * 128 + ks * 32 + lg * 8) ^ ((l15 & 7) << 3)];
            f16x8 bf1 = *(const f16x8*)&ph_c[((16 + l15) * 128 + ks * 32 + lg * 8) ^ (((16 + l15) & 7) << 3)];
            S0 = __builtin_amdgcn_mfma_f32_16x16x32_f16(bf0, ath[ks], S0, 0, 0, 0);
            S1 = __builtin_amdgcn_mfma_f32_16x16x32_f16(bf1, ath[ks], S1, 0, 0, 0);
        }

        // ---- online softmax, log2 domain, scalar per lane ----
        float v = fmaxf(fmaxf(fmaxf(S0[0], S0[1]), fmaxf(S0[2], S0[3])),
                        fmaxf(fmaxf(S1[0], S1[1]), fmaxf(S1[2], S1[3])));
        v = fmaxf(v, __shfl_xor(v, 16));
        v = fmaxf(v, __shfl_xor(v, 32));
        if (__any(v - m_run > 11.5f)) {   // T13 defer-max
            float mn = fmaxf(m_run, v);
            float al = __builtin_amdgcn_exp2f(m_run - mn);
            m_run = mn;
#pragma unroll
            for (int i = 0; i < 8; i++) {
#pragma unroll
                for (int r = 0; r < 4; r++) Y[i][r] *= al;
            }
#pragma unroll
            for (int r = 0; r < 4; r++) Yl[r] *= al;
        }
        float p0[4], p1[4];
#pragma unroll
        for (int r = 0; r < 4; r++) {
            p0[r] = __builtin_amdgcn_exp2f(S0[r] - m_run);
            p1[r] = __builtin_amdgcn_exp2f(S1[r] - m_run);
        }

        // ---- P^T -> LDS [q][key], two packed b64 writes ----
        *(uint2*)&pw[(l15 * 32 + lg * 4) ^ psw] =
            make_uint2(pk2h(p0[0], p0[1]), pk2h(p0[2], p0[3]));
        *(uint2*)&pw[(l15 * 32 + 16 + lg * 4) ^ psw] =
            make_uint2(pk2h(p1[0], p1[1]), pk2h(p1[2], p1[3]));
        __builtin_amdgcn_sched_barrier(0);

        // ---- PV^T: Y^T[d][q] += V[d][k] · P^T[k][q] ----
        f16x8 pb = *(const f16x8*)&pw[(l15 * 32 + lg * 8) ^ psw];
        Yl = __builtin_amdgcn_mfma_f32_16x16x32_f16(ones, pb, Yl, 0, 0, 0);
#pragma unroll
        for (int dt = 0; dt < 8; dt++) {
            int d = dt * 16 + l15;
            f16x8 av = *(const f16x8*)&v_c[(d * 32 + lg * 8) ^ (((d >> 1) & 3) << 3)];
            Y[dt] = __builtin_amdgcn_mfma_f32_16x16x32_f16(av, pb, Y[dt], 0, 0, 0);
        }
        __syncthreads();
    }

    // ---- flash-combine: group 1 exports partials (kv area is dead now) ----
    float* cmb = (float*)kv_s[2];   // 32 KB [64 q][128 d] f32, swz ^((q&7)<<2)
    int q = wq * 16 + l15;
    if (grp == 1) {
        if (lg == 0) {
            cm[q] = m_run;
            cl[q] = Yl[0];
        }
#pragma unroll
        for (int dt = 0; dt < 8; dt++)
            *(f32x4*)&cmb[(q * 128 + dt * 16 + lg * 4) ^ ((q & 7) << 2)] = Y[dt];
    }
    __syncthreads();

    // ---- group 0 merges (exact), normalizes, writes y -> LDS ----
    u16* yl = (u16*)kv_s[0];   // 16 KB [64 n][128 ci], swz ^((n&7)<<3)
    if (grp == 0) {
        float m1 = cm[q], l1 = cl[q];
        float mm = fmaxf(m_run, m1);
        float a0 = __builtin_amdgcn_exp2f(m_run - mm);
        float a1 = __builtin_amdgcn_exp2f(m1 - mm);
        float linv = 1.f / (Yl[0] * a0 + l1 * a1);
#pragma unroll
        for (int dt = 0; dt < 8; dt++) {
            f32x4 c4 = *(const f32x4*)&cmb[(q * 128 + dt * 16 + lg * 4) ^ ((q & 7) << 2)];
            float y0 = (Y[dt][0] * a0 + c4[0] * a1) * linv;
            float y1 = (Y[dt][1] * a0 + c4[1] * a1) * linv;
            float y2 = (Y[dt][2] * a0 + c4[2] * a1) * linv;
            float y3 = (Y[dt][3] * a0 + c4[3] * a1) * linv;
            *(uint2*)&yl[(q * 128 + dt * 16 + lg * 4) ^ ((q & 7) << 3)] =
                make_uint2(pk2h(y0, y1), pk2h(y2, y3));
        }
    }
    __syncthreads();

    // ---- fused final conv: out[c][n] = wf[c][:]·y[n][:], BN, +x (8 waves) ----
    f16x8 bfr[4][4];
#pragma unroll
    for (int ks = 0; ks < 4; ks++)
#pragma unroll
        for (int ct = 0; ct < 4; ct++) {
            int n = ct * 16 + l15;
            bfr[ks][ct] = *(const f16x8*)&yl[(n * 128 + ks * 32 + lg * 8) ^ ((n & 7) << 3)];
        }

#pragma unroll
    for (int rt = 0; rt < 2; rt++) {
        int cb = wid * 32 + rt * 16;   // 8 waves x 2 = 256 c rows
        f16x8 af[4];
#pragma unroll
        for (int ks = 0; ks < 4; ks++)
            af[ks] = *(const f16x8*)(wfh + (size_t)(cb + l15) * 128 + ks * 32 + lg * 8);
        f32x4 acc2[4];
#pragma unroll
        for (int ct = 0; ct < 4; ct++) acc2[ct] = (f32x4){0.f, 0.f, 0.f, 0.f};
#pragma unroll
        for (int ks = 0; ks < 4; ks++)
#pragma unroll
            for (int ct = 0; ct < 4; ct++)
                acc2[ct] = __builtin_amdgcn_mfma_f32_16x16x32_f16(af[ks], bfr[ks][ct], acc2[ct], 0, 0, 0);

        int c4 = cb + lg * 4;
        float4 g4 = *(const float4*)&gam[c4];
        float4 v4 = *(const float4*)&varr[c4];
        float4 m4 = *(const float4*)&mea[c4];
        float4 t4 = *(const float4*)&bet[c4];
        float4 f4 = *(const float4*)&bfi[c4];
        float iv[4], mn[4], bt[4], bv[4];
        iv[0] = g4.x / sqrtf(v4.x + 1e-5f); iv[1] = g4.y / sqrtf(v4.y + 1e-5f);
        iv[2] = g4.z / sqrtf(v4.z + 1e-5f); iv[3] = g4.w / sqrtf(v4.w + 1e-5f);
        mn[0] = m4.x; mn[1] = m4.y; mn[2] = m4.z; mn[3] = m4.w;
        bt[0] = t4.x; bt[1] = t4.y; bt[2] = t4.z; bt[3] = t4.w;
        bv[0] = f4.x; bv[1] = f4.y; bv[2] = f4.z; bv[3] = f4.w;
#pragma unroll
        for (int ct = 0; ct < 4; ct++) {
            int n = qb * 64 + ct * 16 + l15;
#pragma unroll
            for (int r = 0; r < 4; r++) {
                size_t o = ((size_t)(b * CC + c4 + r)) * NN + n;
                out[o] = (acc2[ct][r] + bv[r] - mn[r]) * iv[r] + bt[r] + x[o];
            }
        }
    }
#undef LOADKV
#undef WRITEKV
}

// ---------------------------------------------------------------------------
extern "C" void kernel_launch(void* const* d_in, const int* in_sizes, int n_in,
                              void* d_out, int out_size, void* d_ws, size_t ws_size,
                              hipStream_t stream)
{
    const int NOUT = BB * CC * NN;   // 8,388,608 elements
    bool sizes_ok = (n_in == 13) && (out_size == NOUT) &&
        in_sizes[0] == NOUT &&
        in_sizes[1] == CI * CC && in_sizes[2] == CI &&
        in_sizes[3] == CI * CC && in_sizes[4] == CI &&
        in_sizes[5] == CI * CC && in_sizes[6] == CI &&
        in_sizes[7] == CC * CI && in_sizes[8] == CC &&
        in_sizes[9] == CC && in_sizes[10] == CC && in_sizes[11] == CC && in_sizes[12] == CC;
    if (!sizes_ok || ws_size < (size_t)WS_NEED) {
        float sig = (!sizes_ok) ? 25000.f : 20000.f;
        hipLaunchKernelGGL(fill_constf, dim3((NOUT + 255) / 256), dim3(256), 0, stream,
                           (float*)d_out, sig, NOUT);
        return;
    }

    const float* x   = (const float*)d_in[0];
    const float* wth = (const float*)d_in[1];
    const float* bth = (const float*)d_in[2];
    const float* wph = (const float*)d_in[3];
    const float* bph = (const float*)d_in[4];
    const float* wg  = (const float*)d_in[5];
    const float* bg  = (const float*)d_in[6];
    const float* wf  = (const float*)d_in[7];
    const float* bfi = (const float*)d_in[8];
    const float* gam = (const float*)d_in[9];
    const float* bet = (const float*)d_in[10];
    const float* mea = (const float*)d_in[11];
    const float* var = (const float*)d_in[12];

    char* ws = (char*)d_ws;
    float* outF = (float*)d_out;                   // 33,554,432 B fp32
    u16*   thA  = (u16*)(outF + 4194304);          // theta b=0,1: d_out [16MB, 20MB)
    u16*   thB  = (u16*)(ws + THB_OFF);            // theta b=2,3: ws, 4 MB
    u16*   phHp = (u16*)(ws + PHI_OFF);
    u16*   gHp  = (u16*)(ws + GP_OFF);
    u16*   wFh  = (u16*)(ws + WFH_OFF);
    u32*   part = (u32*)(ws + PART_OFF);
    u32*   w32  = (u32*)ws;

    hipLaunchKernelGGL(proj_mfma, dim3(128, 3, 4), dim3(256), 0, stream,
                       x, bth, bph, bg, wth, wph, wg, wf,
                       thA, thB, phHp, gHp, wFh, part, w32);

    // Single cooperative launch: 512 blocks = 2/CU; grid.sync() inside closes
    // the thA (d_out) read-vs-write hazard across batches.
    int b0c = 0, coop1 = 1;
    void* kargs[] = {
        (void*)&thA, (void*)&thB, (void*)&phHp, (void*)&gHp, (void*)&wFh,
        (void*)&bfi, (void*)&gam, (void*)&bet, (void*)&mea, (void*)&var,
        (void*)&x, (void*)&part, (void*)&w32, (void*)&outF,
        (void*)&b0c, (void*)&coop1
    };
    hipError_t er = hipLaunchCooperativeKernel((void*)attn_fused, dim3(128, 4), dim3(512),
                                               kargs, 0, stream);
    if (er != hipSuccess) {
        // Fallback: proven 2-launch path (stream order serializes the hazard).
        hipLaunchKernelGGL(attn_fused, dim3(128, 2), dim3(512), 0, stream,
                           thA, thB, phHp, gHp, wFh, bfi, gam, bet, mea, var,
                           x, part, w32, outF, 0, 0);
        hipLaunchKernelGGL(attn_fused, dim3(128, 2), dim3(512), 0, stream,
                           thA, thB, phHp, gHp, wFh, bfi, gam, bet, mea, var,
                           x, part, w32, outF, 2, 0);
    }
}